// Round 4
// baseline (334.162 us; speedup 1.0000x reference)
//
#include <hip/hip_runtime.h>
#include <math.h>

// GAT 2-layer: N=10000, E=160000 (+N self loops), IN=128, H1=8, C1=128, OUT=64.
// R4: occupancy-oriented GEMM restructure.
//   l1_gemm: block=(32-node tile, head), 16 KB LDS, grid 2504.
//   l2_transform: block=16 nodes, k-chunked 16 KB staging, grid 626.

#define NEG_SLOPE 0.2f

__device__ __forceinline__ float leaky(float v) { return v >= 0.0f ? v : NEG_SLOPE * v; }

// ---------------- CSR build ----------------

__global__ void count_kernel(const int* __restrict__ ei, int* __restrict__ counts, int E, int N) {
    int i = blockIdx.x * blockDim.x + threadIdx.x;
    int M = E + N;
    if (i >= M) return;
    int dst = (i < E) ? ei[E + i] : (i - E);   // self-loop tail
    atomicAdd(&counts[dst], 1);
}

__global__ __launch_bounds__(1024) void scan_kernel(
    const int* __restrict__ counts, int* __restrict__ offsets,
    int* __restrict__ cursor, int N) {
    __shared__ int sums[1024];
    int t = threadIdx.x;
    int per = (N + 1023) / 1024;
    int base = t * per;
    int s = 0;
    for (int j = 0; j < per; j++) {
        int idx = base + j;
        if (idx < N) s += counts[idx];
    }
    sums[t] = s;
    __syncthreads();
    int acc = s;
    for (int off = 1; off < 1024; off <<= 1) {
        int v = (t >= off) ? sums[t - off] : 0;
        __syncthreads();
        acc += v;
        sums[t] = acc;
        __syncthreads();
    }
    int run = acc - s;
    for (int j = 0; j < per; j++) {
        int idx = base + j;
        if (idx < N) {
            offsets[idx] = run;
            cursor[idx] = run;
            run += counts[idx];
        }
    }
    if (t == 1023) offsets[N] = run;
}

__global__ void fill_kernel(const int* __restrict__ ei, int* __restrict__ cursor,
                            int* __restrict__ srcs, int E, int N) {
    int i = blockIdx.x * blockDim.x + threadIdx.x;
    int M = E + N;
    if (i >= M) return;
    int src, dst;
    if (i < E) { src = ei[i]; dst = ei[E + i]; }
    else       { src = dst = i - E; }
    int pos = atomicAdd(&cursor[dst], 1);
    srcs[pos] = src;
}

// ---------------- prep: As[k,h] = sum_c W1[k,h*128+c]*a_src1[h,c]  (and Ad) ----

__global__ __launch_bounds__(256) void prep_kernel(
    const float* __restrict__ W1, const float* __restrict__ a_src1,
    const float* __restrict__ a_dst1, float* __restrict__ As, float* __restrict__ Ad) {
    int i = blockIdx.x * 256 + threadIdx.x;   // 0..1023
    int k = i >> 3, h = i & 7;
    float ss = 0.f, sd = 0.f;
    for (int c = 0; c < 128; c += 4) {
        float4 w = *(const float4*)(W1 + (size_t)k * 1024 + h * 128 + c);
        float4 a = *(const float4*)(a_src1 + h * 128 + c);
        float4 d = *(const float4*)(a_dst1 + h * 128 + c);
        ss += w.x * a.x + w.y * a.y + w.z * a.z + w.w * a.w;
        sd += w.x * d.x + w.y * d.y + w.z * d.z + w.w * d.w;
    }
    As[k * 8 + h] = ss;
    Ad[k * 8 + h] = sd;
}

// ---------------- alpha1: as1/ad1 = x @ As / Ad  [N,8] ----------------

__global__ __launch_bounds__(256) void alpha1_kernel(
    const float* __restrict__ x, const float* __restrict__ As, const float* __restrict__ Ad,
    float* __restrict__ as1, float* __restrict__ ad1, int N) {
    __shared__ float sAs[1024], sAd[1024];
    int t = threadIdx.x;
    {
        int i = t * 4;
        *(float4*)(sAs + i) = *(const float4*)(As + i);
        *(float4*)(sAd + i) = *(const float4*)(Ad + i);
    }
    __syncthreads();
    int node = blockIdx.x * 32 + (t >> 3);
    int h = t & 7;
    if (node >= N) return;
    float accs = 0.f, accd = 0.f;
    for (int k = 0; k < 128; k += 4) {
        float4 xv = *(const float4*)(x + (size_t)node * 128 + k);
        accs += xv.x * sAs[k * 8 + h] + xv.y * sAs[(k + 1) * 8 + h]
              + xv.z * sAs[(k + 2) * 8 + h] + xv.w * sAs[(k + 3) * 8 + h];
        accd += xv.x * sAd[k * 8 + h] + xv.y * sAd[(k + 1) * 8 + h]
              + xv.z * sAd[(k + 2) * 8 + h] + xv.w * sAd[(k + 3) * 8 + h];
    }
    as1[node * 8 + h] = accs;
    ad1[node * 8 + h] = accd;
}

// ---------------- l1_aggx: y[n,h,:] = sum_e softmax-w * x[src,:] -----------

#define CHUNK 256

__global__ __launch_bounds__(256) void l1_aggx(
    const float* __restrict__ x, const float* __restrict__ as1, const float* __restrict__ ad1,
    const int* __restrict__ offsets, const int* __restrict__ srcs,
    float* __restrict__ y, int N) {
    int n = blockIdx.x;
    int t = threadIdx.x;
    int beg = offsets[n];
    int deg = offsets[n + 1] - beg;
    __shared__ int   ssrc[CHUNK];
    __shared__ float wsh[CHUNK * 8];
    __shared__ float ad[8], mh[8];
    __shared__ float red[256];
    if (t < 8) ad[t] = ad1[n * 8 + t];
    __syncthreads();
    // phase A: per-head max (8 heads x 32 edge-lanes)
    int h8 = t & 7, el = t >> 3;
    float m = -3.4e38f;
    for (int i = el; i < deg; i += 32) {
        int s = srcs[beg + i];
        m = fmaxf(m, leaky(as1[s * 8 + h8] + ad[h8]));
    }
    red[t] = m;
    __syncthreads();
    for (int off = 128; off >= 8; off >>= 1) {
        if (t < off) red[t] = fmaxf(red[t], red[t + off]);
        __syncthreads();
    }
    if (t < 8) mh[t] = red[t];
    __syncthreads();
    // phase B: chunked softmax-weight staging + x-row gather accumulate
    int h = t >> 5;
    int k0 = (t & 31) * 4;
    float ax = 0.f, ay = 0.f, az = 0.f, aw = 0.f, ssum = 0.f;
    for (int cb = 0; cb < deg; cb += CHUNK) {
        int cd = min(CHUNK, deg - cb);
        if (t < cd) ssrc[t] = srcs[beg + cb + t];
        __syncthreads();
        for (int idx = t; idx < cd * 8; idx += 256) {
            int i = idx >> 3, hx = idx & 7;
            int s = ssrc[i];
            wsh[idx] = __expf(leaky(as1[s * 8 + hx] + ad[hx]) - mh[hx]);
        }
        __syncthreads();
        int i = 0;
        for (; i + 1 < cd; i += 2) {
            int s0 = ssrc[i], s1 = ssrc[i + 1];
            float w0 = wsh[i * 8 + h], w1 = wsh[(i + 1) * 8 + h];
            float4 v0 = *(const float4*)(x + (size_t)s0 * 128 + k0);
            float4 v1 = *(const float4*)(x + (size_t)s1 * 128 + k0);
            ax = fmaf(w0, v0.x, ax); ay = fmaf(w0, v0.y, ay);
            az = fmaf(w0, v0.z, az); aw = fmaf(w0, v0.w, aw);
            ax = fmaf(w1, v1.x, ax); ay = fmaf(w1, v1.y, ay);
            az = fmaf(w1, v1.z, az); aw = fmaf(w1, v1.w, aw);
            ssum += w0 + w1;
        }
        if (i < cd) {
            int s0 = ssrc[i];
            float w0 = wsh[i * 8 + h];
            float4 v0 = *(const float4*)(x + (size_t)s0 * 128 + k0);
            ax = fmaf(w0, v0.x, ax); ay = fmaf(w0, v0.y, ay);
            az = fmaf(w0, v0.z, az); aw = fmaf(w0, v0.w, aw);
            ssum += w0;
        }
        __syncthreads();
    }
    float inv = 1.0f / (ssum + 1e-16f);
    *(float4*)(y + (size_t)n * 1024 + t * 4) =
        make_float4(ax * inv, ay * inv, az * inv, aw * inv);
}

// ---------------- l1_gemm: hbuf = ELU(per-head y @ W1 + b1) ----------------
// Block = (32-node tile, head h). 16 KB LDS. Thread: c0=(t&31)*4, node-group
// ng=t>>5 owning 4 nodes. Grid = ceil(N/32)*8 = 2504.

__global__ __launch_bounds__(256) void l1_gemm(
    const float* __restrict__ y, const float* __restrict__ W1,
    const float* __restrict__ b1, float* __restrict__ hbuf, int N) {
    int h = blockIdx.x & 7;
    int nb = (blockIdx.x >> 3) * 32;
    int t = threadIdx.x;
    __shared__ float ys[32 * 128];   // 16 KB
#pragma unroll
    for (int r = 0; r < 4; r++) {
        int idx = r * 1024 + t * 4;      // 0..4095
        int nd = idx >> 7, k = idx & 127;
        int node = nb + nd;
        float4 v = make_float4(0.f, 0.f, 0.f, 0.f);
        if (node < N) v = *(const float4*)(y + (size_t)node * 1024 + h * 128 + k);
        *(float4*)(ys + idx) = v;
    }
    __syncthreads();
    int c0 = (t & 31) * 4;   // channel within head
    int ng = t >> 5;         // node group: nodes ng*4 .. ng*4+3
    float4 acc[4];
#pragma unroll
    for (int nd = 0; nd < 4; nd++) acc[nd] = make_float4(0.f, 0.f, 0.f, 0.f);
    const float* Wc = W1 + h * 128 + c0;
    for (int k = 0; k < 128; k += 4) {
        float4 w0 = *(const float4*)(Wc + (size_t)(k + 0) * 1024);
        float4 w1 = *(const float4*)(Wc + (size_t)(k + 1) * 1024);
        float4 w2 = *(const float4*)(Wc + (size_t)(k + 2) * 1024);
        float4 w3 = *(const float4*)(Wc + (size_t)(k + 3) * 1024);
#pragma unroll
        for (int nd = 0; nd < 4; nd++) {
            float4 yv = *(const float4*)(ys + (ng * 4 + nd) * 128 + k);
            acc[nd].x = fmaf(yv.x, w0.x, acc[nd].x);
            acc[nd].y = fmaf(yv.x, w0.y, acc[nd].y);
            acc[nd].z = fmaf(yv.x, w0.z, acc[nd].z);
            acc[nd].w = fmaf(yv.x, w0.w, acc[nd].w);
            acc[nd].x = fmaf(yv.y, w1.x, acc[nd].x);
            acc[nd].y = fmaf(yv.y, w1.y, acc[nd].y);
            acc[nd].z = fmaf(yv.y, w1.z, acc[nd].z);
            acc[nd].w = fmaf(yv.y, w1.w, acc[nd].w);
            acc[nd].x = fmaf(yv.z, w2.x, acc[nd].x);
            acc[nd].y = fmaf(yv.z, w2.y, acc[nd].y);
            acc[nd].z = fmaf(yv.z, w2.z, acc[nd].z);
            acc[nd].w = fmaf(yv.z, w2.w, acc[nd].w);
            acc[nd].x = fmaf(yv.w, w3.x, acc[nd].x);
            acc[nd].y = fmaf(yv.w, w3.y, acc[nd].y);
            acc[nd].z = fmaf(yv.w, w3.z, acc[nd].z);
            acc[nd].w = fmaf(yv.w, w3.w, acc[nd].w);
        }
    }
    float4 bv = *(const float4*)(b1 + h * 128 + c0);
#pragma unroll
    for (int nd = 0; nd < 4; nd++) {
        int node = nb + ng * 4 + nd;
        if (node >= N) break;
        float ox = acc[nd].x + bv.x;
        float oy = acc[nd].y + bv.y;
        float oz = acc[nd].z + bv.z;
        float ow = acc[nd].w + bv.w;
        ox = ox > 0.f ? ox : expm1f(ox);
        oy = oy > 0.f ? oy : expm1f(oy);
        oz = oz > 0.f ? oz : expm1f(oz);
        ow = ow > 0.f ? ow : expm1f(ow);
        *(float4*)(hbuf + (size_t)node * 1024 + h * 128 + c0) = make_float4(ox, oy, oz, ow);
    }
}

// ---------------- Layer 2 transform: h2 = hbuf @ W2, alpha_s2/alpha_d2 ------
// Block = 16 nodes, k-chunked staging (16 KB). Thread: cg=t&15 (4 channels),
// ng=t>>4 (node). Grid = ceil(N/16) = 626.

__global__ __launch_bounds__(256) void l2_transform(
    const float* __restrict__ hbuf, const float* __restrict__ W2,
    const float* __restrict__ a_src2, const float* __restrict__ a_dst2,
    float* __restrict__ h2, float* __restrict__ as2, float* __restrict__ ad2, int N) {
    int nb = blockIdx.x * 16;
    int t = threadIdx.x;
    __shared__ float hs[16 * 256];   // 16 KB per k-chunk
    int cg = t & 15, ng = t >> 4;
    int c0 = cg * 4;
    float4 acc = make_float4(0.f, 0.f, 0.f, 0.f);
    for (int kc = 0; kc < 1024; kc += 256) {
        // stage 16x256 floats = 16 per thread = 4 float4
#pragma unroll
        for (int r = 0; r < 4; r++) {
            int idx = r * 1024 + t * 4;   // 0..4095
            int nd = idx >> 8, k = idx & 255;
            int node = nb + nd;
            float4 v = make_float4(0.f, 0.f, 0.f, 0.f);
            if (node < N) v = *(const float4*)(hbuf + (size_t)node * 1024 + kc + k);
            *(float4*)(hs + idx) = v;
        }
        __syncthreads();
        const float* Wc = W2 + (size_t)kc * 64 + c0;
        for (int k = 0; k < 256; k += 4) {
            float4 w0 = *(const float4*)(Wc + (size_t)(k + 0) * 64);
            float4 w1 = *(const float4*)(Wc + (size_t)(k + 1) * 64);
            float4 w2 = *(const float4*)(Wc + (size_t)(k + 2) * 64);
            float4 w3 = *(const float4*)(Wc + (size_t)(k + 3) * 64);
            float4 yv = *(const float4*)(hs + ng * 256 + k);
            acc.x = fmaf(yv.x, w0.x, acc.x);
            acc.y = fmaf(yv.x, w0.y, acc.y);
            acc.z = fmaf(yv.x, w0.z, acc.z);
            acc.w = fmaf(yv.x, w0.w, acc.w);
            acc.x = fmaf(yv.y, w1.x, acc.x);
            acc.y = fmaf(yv.y, w1.y, acc.y);
            acc.z = fmaf(yv.y, w1.z, acc.z);
            acc.w = fmaf(yv.y, w1.w, acc.w);
            acc.x = fmaf(yv.z, w2.x, acc.x);
            acc.y = fmaf(yv.z, w2.y, acc.y);
            acc.z = fmaf(yv.z, w2.z, acc.z);
            acc.w = fmaf(yv.z, w2.w, acc.w);
            acc.x = fmaf(yv.w, w3.x, acc.x);
            acc.y = fmaf(yv.w, w3.y, acc.y);
            acc.z = fmaf(yv.w, w3.z, acc.z);
            acc.w = fmaf(yv.w, w3.w, acc.w);
        }
        __syncthreads();
    }
    int node = nb + ng;
    float4 av = *(const float4*)(a_src2 + c0);
    float4 dv = *(const float4*)(a_dst2 + c0);
    float ps = acc.x * av.x + acc.y * av.y + acc.z * av.z + acc.w * av.w;
    float pd = acc.x * dv.x + acc.y * dv.y + acc.z * dv.z + acc.w * dv.w;
#pragma unroll
    for (int mm = 1; mm <= 8; mm <<= 1) {   // reduce over 16 cg lanes (same ng)
        ps += __shfl_xor(ps, mm);
        pd += __shfl_xor(pd, mm);
    }
    if (node < N) {
        *(float4*)(h2 + (size_t)node * 64 + c0) = acc;
        if (cg == 0) { as2[node] = ps; ad2[node] = pd; }
    }
}

// ---------------- Layer 2 aggregate ----------------

__global__ __launch_bounds__(256) void l2_agg(
    const float* __restrict__ h2, const float* __restrict__ as2, const float* __restrict__ ad2,
    const float* __restrict__ b2, const int* __restrict__ offsets, const int* __restrict__ srcs,
    float* __restrict__ out, int N) {
    int n = blockIdx.x;
    int t = threadIdx.x;
    int beg = offsets[n];
    int deg = offsets[n + 1] - beg;
    __shared__ int   ssrc[CHUNK];
    __shared__ float wsh[CHUNK];
    __shared__ float red[256];
    __shared__ float m_sh, s_sh;
    float adn = ad2[n];
    float m = -3.4e38f;
    for (int i = t; i < deg; i += 256) m = fmaxf(m, leaky(as2[srcs[beg + i]] + adn));
    red[t] = m;
    __syncthreads();
    for (int off = 128; off >= 1; off >>= 1) {
        if (t < off) red[t] = fmaxf(red[t], red[t + off]);
        __syncthreads();
    }
    if (t == 0) m_sh = red[0];
    __syncthreads();
    float mv = m_sh;
    int c = t & 63, eg = t >> 6;
    float acc = 0.f, wpart = 0.f;
    for (int cb = 0; cb < deg; cb += CHUNK) {
        int cd = min(CHUNK, deg - cb);
        if (t < cd) {
            int s = srcs[beg + cb + t];
            ssrc[t] = s;
            float w = __expf(leaky(as2[s] + adn) - mv);
            wsh[t] = w;
            wpart += w;
        }
        __syncthreads();
        for (int i = eg; i < cd; i += 4)
            acc = fmaf(wsh[i], h2[(size_t)ssrc[i] * 64 + c], acc);
        __syncthreads();
    }
    red[t] = wpart;
    __syncthreads();
    for (int off = 128; off >= 1; off >>= 1) {
        if (t < off) red[t] += red[t + off];
        __syncthreads();
    }
    if (t == 0) s_sh = red[0] + 1e-16f;
    __syncthreads();
    float stot = s_sh;
    red[t] = acc;
    __syncthreads();
    if (t < 128) red[t] += red[t + 128];
    __syncthreads();
    if (t < 64) {
        float v = red[t] + red[t + 64];
        out[(size_t)n * 64 + t] = v / stot + b2[t];
    }
}

// ---------------- launch ----------------

static inline size_t align_up(size_t v, size_t a) { return (v + a - 1) / a * a; }

extern "C" void kernel_launch(void* const* d_in, const int* in_sizes, int n_in,
                              void* d_out, int out_size, void* d_ws, size_t ws_size,
                              hipStream_t stream) {
    const float* x      = (const float*)d_in[0];
    const int*   ei     = (const int*)d_in[1];
    const float* W1     = (const float*)d_in[2];
    const float* a_src1 = (const float*)d_in[3];
    const float* a_dst1 = (const float*)d_in[4];
    const float* b1     = (const float*)d_in[5];
    const float* W2     = (const float*)d_in[6];
    const float* a_src2 = (const float*)d_in[7];
    const float* a_dst2 = (const float*)d_in[8];
    const float* b2     = (const float*)d_in[9];
    float* out = (float*)d_out;

    int N = in_sizes[0] / 128;
    int E = in_sizes[1] / 2;
    int M = E + N;

    char* p = (char*)d_ws;
    size_t off = 0;
    auto carve = [&](size_t bytes) {
        void* r = p + off;
        off = align_up(off + bytes, 256);
        return r;
    };
    int*   counts  = (int*)carve((size_t)N * 4);
    int*   offsets = (int*)carve((size_t)(N + 1) * 4);
    int*   cursor  = (int*)carve((size_t)N * 4);
    int*   srcs    = (int*)carve((size_t)M * 4);
    float* As      = (float*)carve(1024 * 4);
    float* Ad      = (float*)carve(1024 * 4);
    float* as1     = (float*)carve((size_t)N * 8 * 4);
    float* ad1     = (float*)carve((size_t)N * 8 * 4);
    float* as2     = (float*)carve((size_t)N * 4);
    float* ad2     = (float*)carve((size_t)N * 4);
    float* h2      = (float*)carve((size_t)N * 64 * 4);
    float* y       = (float*)carve((size_t)N * 1024 * 4);
    float* hbuf    = (float*)carve((size_t)N * 1024 * 4);
    (void)ws_size; // ~86 MB

    hipMemsetAsync(counts, 0, (size_t)N * 4, stream);
    prep_kernel<<<4, 256, 0, stream>>>(W1, a_src1, a_dst1, As, Ad);
    alpha1_kernel<<<(N + 31) / 32, 256, 0, stream>>>(x, As, Ad, as1, ad1, N);
    count_kernel<<<(M + 255) / 256, 256, 0, stream>>>(ei, counts, E, N);
    scan_kernel<<<1, 1024, 0, stream>>>(counts, offsets, cursor, N);
    fill_kernel<<<(M + 255) / 256, 256, 0, stream>>>(ei, cursor, srcs, E, N);
    l1_aggx<<<N, 256, 0, stream>>>(x, as1, ad1, offsets, srcs, y, N);
    l1_gemm<<<((N + 31) / 32) * 8, 256, 0, stream>>>(y, W1, b1, hbuf, N);
    l2_transform<<<(N + 15) / 16, 256, 0, stream>>>(hbuf, W2, a_src2, a_dst2, h2, as2, ad2, N);
    l2_agg<<<N, 256, 0, stream>>>(h2, as2, ad2, b2, offsets, srcs, out, N);
}

// Round 5
// 271.851 us; speedup vs baseline: 1.2292x; 1.2292x over previous
//
#include <hip/hip_runtime.h>
#include <math.h>

// GAT 2-layer: N=10000, E=160000 (+N self loops), IN=128, H1=8, C1=128, OUT=64.
// R5: weight-read-once-per-block GEMMs with 32 KB LDS for occupancy.
//   l1_gemm: 8 nodes/block, thread owns column c0=t*4, grid 1250.
//   l2_transform: split-K, 4 nodes/block, part[] reduction, grid 2500,
//                 kb-staggered LDS reads (bank-conflict-free).

#define NEG_SLOPE 0.2f

__device__ __forceinline__ float leaky(float v) { return v >= 0.0f ? v : NEG_SLOPE * v; }

// ---------------- CSR build ----------------

__global__ void count_kernel(const int* __restrict__ ei, int* __restrict__ counts, int E, int N) {
    int i = blockIdx.x * blockDim.x + threadIdx.x;
    int M = E + N;
    if (i >= M) return;
    int dst = (i < E) ? ei[E + i] : (i - E);   // self-loop tail
    atomicAdd(&counts[dst], 1);
}

__global__ __launch_bounds__(1024) void scan_kernel(
    const int* __restrict__ counts, int* __restrict__ offsets,
    int* __restrict__ cursor, int N) {
    __shared__ int sums[1024];
    int t = threadIdx.x;
    int per = (N + 1023) / 1024;
    int base = t * per;
    int s = 0;
    for (int j = 0; j < per; j++) {
        int idx = base + j;
        if (idx < N) s += counts[idx];
    }
    sums[t] = s;
    __syncthreads();
    int acc = s;
    for (int off = 1; off < 1024; off <<= 1) {
        int v = (t >= off) ? sums[t - off] : 0;
        __syncthreads();
        acc += v;
        sums[t] = acc;
        __syncthreads();
    }
    int run = acc - s;
    for (int j = 0; j < per; j++) {
        int idx = base + j;
        if (idx < N) {
            offsets[idx] = run;
            cursor[idx] = run;
            run += counts[idx];
        }
    }
    if (t == 1023) offsets[N] = run;
}

__global__ void fill_kernel(const int* __restrict__ ei, int* __restrict__ cursor,
                            int* __restrict__ srcs, int E, int N) {
    int i = blockIdx.x * blockDim.x + threadIdx.x;
    int M = E + N;
    if (i >= M) return;
    int src, dst;
    if (i < E) { src = ei[i]; dst = ei[E + i]; }
    else       { src = dst = i - E; }
    int pos = atomicAdd(&cursor[dst], 1);
    srcs[pos] = src;
}

// ---------------- prep: As[k,h] = sum_c W1[k,h*128+c]*a_src1[h,c]  (and Ad) ----

__global__ __launch_bounds__(256) void prep_kernel(
    const float* __restrict__ W1, const float* __restrict__ a_src1,
    const float* __restrict__ a_dst1, float* __restrict__ As, float* __restrict__ Ad) {
    int i = blockIdx.x * 256 + threadIdx.x;   // 0..1023
    int k = i >> 3, h = i & 7;
    float ss = 0.f, sd = 0.f;
    for (int c = 0; c < 128; c += 4) {
        float4 w = *(const float4*)(W1 + (size_t)k * 1024 + h * 128 + c);
        float4 a = *(const float4*)(a_src1 + h * 128 + c);
        float4 d = *(const float4*)(a_dst1 + h * 128 + c);
        ss += w.x * a.x + w.y * a.y + w.z * a.z + w.w * a.w;
        sd += w.x * d.x + w.y * d.y + w.z * d.z + w.w * d.w;
    }
    As[k * 8 + h] = ss;
    Ad[k * 8 + h] = sd;
}

// ---------------- alpha1: as1/ad1 = x @ As / Ad  [N,8] ----------------

__global__ __launch_bounds__(256) void alpha1_kernel(
    const float* __restrict__ x, const float* __restrict__ As, const float* __restrict__ Ad,
    float* __restrict__ as1, float* __restrict__ ad1, int N) {
    __shared__ float sAs[1024], sAd[1024];
    int t = threadIdx.x;
    {
        int i = t * 4;
        *(float4*)(sAs + i) = *(const float4*)(As + i);
        *(float4*)(sAd + i) = *(const float4*)(Ad + i);
    }
    __syncthreads();
    int node = blockIdx.x * 32 + (t >> 3);
    int h = t & 7;
    if (node >= N) return;
    float accs = 0.f, accd = 0.f;
    for (int k = 0; k < 128; k += 4) {
        float4 xv = *(const float4*)(x + (size_t)node * 128 + k);
        accs += xv.x * sAs[k * 8 + h] + xv.y * sAs[(k + 1) * 8 + h]
              + xv.z * sAs[(k + 2) * 8 + h] + xv.w * sAs[(k + 3) * 8 + h];
        accd += xv.x * sAd[k * 8 + h] + xv.y * sAd[(k + 1) * 8 + h]
              + xv.z * sAd[(k + 2) * 8 + h] + xv.w * sAd[(k + 3) * 8 + h];
    }
    as1[node * 8 + h] = accs;
    ad1[node * 8 + h] = accd;
}

// ---------------- l1_aggx: y[n,h,:] = sum_e softmax-w * x[src,:] -----------

#define CHUNK 256

__global__ __launch_bounds__(256) void l1_aggx(
    const float* __restrict__ x, const float* __restrict__ as1, const float* __restrict__ ad1,
    const int* __restrict__ offsets, const int* __restrict__ srcs,
    float* __restrict__ y, int N) {
    int n = blockIdx.x;
    int t = threadIdx.x;
    int beg = offsets[n];
    int deg = offsets[n + 1] - beg;
    __shared__ int   ssrc[CHUNK];
    __shared__ float wsh[CHUNK * 8];
    __shared__ float ad[8], mh[8];
    __shared__ float red[256];
    if (t < 8) ad[t] = ad1[n * 8 + t];
    __syncthreads();
    // phase A: per-head max (8 heads x 32 edge-lanes)
    int h8 = t & 7, el = t >> 3;
    float m = -3.4e38f;
    for (int i = el; i < deg; i += 32) {
        int s = srcs[beg + i];
        m = fmaxf(m, leaky(as1[s * 8 + h8] + ad[h8]));
    }
    red[t] = m;
    __syncthreads();
    for (int off = 128; off >= 8; off >>= 1) {
        if (t < off) red[t] = fmaxf(red[t], red[t + off]);
        __syncthreads();
    }
    if (t < 8) mh[t] = red[t];
    __syncthreads();
    // phase B: chunked softmax-weight staging + x-row gather accumulate
    int h = t >> 5;
    int k0 = (t & 31) * 4;
    float ax = 0.f, ay = 0.f, az = 0.f, aw = 0.f, ssum = 0.f;
    for (int cb = 0; cb < deg; cb += CHUNK) {
        int cd = min(CHUNK, deg - cb);
        if (t < cd) ssrc[t] = srcs[beg + cb + t];
        __syncthreads();
        for (int idx = t; idx < cd * 8; idx += 256) {
            int i = idx >> 3, hx = idx & 7;
            int s = ssrc[i];
            wsh[idx] = __expf(leaky(as1[s * 8 + hx] + ad[hx]) - mh[hx]);
        }
        __syncthreads();
        int i = 0;
        for (; i + 1 < cd; i += 2) {
            int s0 = ssrc[i], s1 = ssrc[i + 1];
            float w0 = wsh[i * 8 + h], w1 = wsh[(i + 1) * 8 + h];
            float4 v0 = *(const float4*)(x + (size_t)s0 * 128 + k0);
            float4 v1 = *(const float4*)(x + (size_t)s1 * 128 + k0);
            ax = fmaf(w0, v0.x, ax); ay = fmaf(w0, v0.y, ay);
            az = fmaf(w0, v0.z, az); aw = fmaf(w0, v0.w, aw);
            ax = fmaf(w1, v1.x, ax); ay = fmaf(w1, v1.y, ay);
            az = fmaf(w1, v1.z, az); aw = fmaf(w1, v1.w, aw);
            ssum += w0 + w1;
        }
        if (i < cd) {
            int s0 = ssrc[i];
            float w0 = wsh[i * 8 + h];
            float4 v0 = *(const float4*)(x + (size_t)s0 * 128 + k0);
            ax = fmaf(w0, v0.x, ax); ay = fmaf(w0, v0.y, ay);
            az = fmaf(w0, v0.z, az); aw = fmaf(w0, v0.w, aw);
            ssum += w0;
        }
        __syncthreads();
    }
    float inv = 1.0f / (ssum + 1e-16f);
    *(float4*)(y + (size_t)n * 1024 + t * 4) =
        make_float4(ax * inv, ay * inv, az * inv, aw * inv);
}

// ---------------- l1_gemm: hbuf = ELU(per-head y @ W1 + b1) ----------------
// 8 nodes/block (32 KB LDS), thread owns output column c0 = t*4 so W1 is read
// exactly once per block, fully coalesced. Grid = ceil(N/8) = 1250.

__global__ __launch_bounds__(256) void l1_gemm(
    const float* __restrict__ y, const float* __restrict__ W1,
    const float* __restrict__ b1, float* __restrict__ hbuf, int N) {
    int nb = blockIdx.x * 8;
    int t = threadIdx.x;
    __shared__ float ys[8 * 1024];   // 32 KB
#pragma unroll
    for (int r = 0; r < 8; r++) {
        int idx = r * 1024 + t * 4;
        int node = nb + (idx >> 10);
        float4 v = make_float4(0.f, 0.f, 0.f, 0.f);
        if (node < N) v = *(const float4*)(y + (size_t)node * 1024 + (idx & 1023));
        *(float4*)(ys + idx) = v;
    }
    __syncthreads();
    int c0 = t * 4;
    int hb = (t >> 5) * 128;   // head base in k-space
    float4 acc[8];
#pragma unroll
    for (int nd = 0; nd < 8; nd++) acc[nd] = make_float4(0.f, 0.f, 0.f, 0.f);
    for (int k = 0; k < 128; k += 4) {
        float4 w0 = *(const float4*)(W1 + (size_t)(k + 0) * 1024 + c0);
        float4 w1 = *(const float4*)(W1 + (size_t)(k + 1) * 1024 + c0);
        float4 w2 = *(const float4*)(W1 + (size_t)(k + 2) * 1024 + c0);
        float4 w3 = *(const float4*)(W1 + (size_t)(k + 3) * 1024 + c0);
#pragma unroll
        for (int nd = 0; nd < 8; nd++) {
            float4 yv = *(const float4*)(ys + nd * 1024 + hb + k);  // 2-addr broadcast
            acc[nd].x = fmaf(yv.x, w0.x, acc[nd].x);
            acc[nd].y = fmaf(yv.x, w0.y, acc[nd].y);
            acc[nd].z = fmaf(yv.x, w0.z, acc[nd].z);
            acc[nd].w = fmaf(yv.x, w0.w, acc[nd].w);
            acc[nd].x = fmaf(yv.y, w1.x, acc[nd].x);
            acc[nd].y = fmaf(yv.y, w1.y, acc[nd].y);
            acc[nd].z = fmaf(yv.y, w1.z, acc[nd].z);
            acc[nd].w = fmaf(yv.y, w1.w, acc[nd].w);
            acc[nd].x = fmaf(yv.z, w2.x, acc[nd].x);
            acc[nd].y = fmaf(yv.z, w2.y, acc[nd].y);
            acc[nd].z = fmaf(yv.z, w2.z, acc[nd].z);
            acc[nd].w = fmaf(yv.z, w2.w, acc[nd].w);
            acc[nd].x = fmaf(yv.w, w3.x, acc[nd].x);
            acc[nd].y = fmaf(yv.w, w3.y, acc[nd].y);
            acc[nd].z = fmaf(yv.w, w3.z, acc[nd].z);
            acc[nd].w = fmaf(yv.w, w3.w, acc[nd].w);
        }
    }
    float4 bv = *(const float4*)(b1 + c0);
#pragma unroll
    for (int nd = 0; nd < 8; nd++) {
        int node = nb + nd;
        if (node >= N) break;
        float ox = acc[nd].x + bv.x;
        float oy = acc[nd].y + bv.y;
        float oz = acc[nd].z + bv.z;
        float ow = acc[nd].w + bv.w;
        ox = ox > 0.f ? ox : expm1f(ox);
        oy = oy > 0.f ? oy : expm1f(oy);
        oz = oz > 0.f ? oz : expm1f(oz);
        ow = ow > 0.f ? ow : expm1f(ow);
        *(float4*)(hbuf + (size_t)node * 1024 + c0) = make_float4(ox, oy, oz, ow);
    }
}

// ---------------- Layer 2 transform: h2 = hbuf @ W2, alpha_s2/alpha_d2 ------
// Split-K: 4 nodes/block, thread = (c-group cg=t&15, k-block kb=t>>4 of 64 k).
// W2 read once per block (coalesced). hs reads kb-staggered -> <=2-way banks.
// LDS: hs 16 KB + part 16 KB = 32 KB. Grid = ceil(N/4) = 2500.

__global__ __launch_bounds__(256) void l2_transform(
    const float* __restrict__ hbuf, const float* __restrict__ W2,
    const float* __restrict__ a_src2, const float* __restrict__ a_dst2,
    float* __restrict__ h2, float* __restrict__ as2, float* __restrict__ ad2, int N) {
    int nb = blockIdx.x * 4;
    int t = threadIdx.x;
    __shared__ float hs[4 * 1024];     // 16 KB
    __shared__ float part[16 * 256];   // 16 KB
#pragma unroll
    for (int r = 0; r < 4; r++) {
        int idx = r * 1024 + t * 4;
        int node = nb + (idx >> 10);
        float4 v = make_float4(0.f, 0.f, 0.f, 0.f);
        if (node < N) v = *(const float4*)(hbuf + (size_t)node * 1024 + (idx & 1023));
        *(float4*)(hs + idx) = v;
    }
    __syncthreads();
    int cg = t & 15, kb = t >> 4;
    int c0 = cg * 4;
    int kbase = kb * 64;
    float4 acc[4];
#pragma unroll
    for (int nd = 0; nd < 4; nd++) acc[nd] = make_float4(0.f, 0.f, 0.f, 0.f);
    for (int jj = 0; jj < 64; jj += 4) {
        int k = kbase + ((jj + kb * 16) & 63);   // stagger: <=2-way bank overlap
        float4 w0 = *(const float4*)(W2 + (size_t)(k + 0) * 64 + c0);
        float4 w1 = *(const float4*)(W2 + (size_t)(k + 1) * 64 + c0);
        float4 w2 = *(const float4*)(W2 + (size_t)(k + 2) * 64 + c0);
        float4 w3 = *(const float4*)(W2 + (size_t)(k + 3) * 64 + c0);
#pragma unroll
        for (int nd = 0; nd < 4; nd++) {
            float4 yv = *(const float4*)(hs + nd * 1024 + k);
            acc[nd].x = fmaf(yv.x, w0.x, acc[nd].x);
            acc[nd].y = fmaf(yv.x, w0.y, acc[nd].y);
            acc[nd].z = fmaf(yv.x, w0.z, acc[nd].z);
            acc[nd].w = fmaf(yv.x, w0.w, acc[nd].w);
            acc[nd].x = fmaf(yv.y, w1.x, acc[nd].x);
            acc[nd].y = fmaf(yv.y, w1.y, acc[nd].y);
            acc[nd].z = fmaf(yv.y, w1.z, acc[nd].z);
            acc[nd].w = fmaf(yv.y, w1.w, acc[nd].w);
            acc[nd].x = fmaf(yv.z, w2.x, acc[nd].x);
            acc[nd].y = fmaf(yv.z, w2.y, acc[nd].y);
            acc[nd].z = fmaf(yv.z, w2.z, acc[nd].z);
            acc[nd].w = fmaf(yv.z, w2.w, acc[nd].w);
            acc[nd].x = fmaf(yv.w, w3.x, acc[nd].x);
            acc[nd].y = fmaf(yv.w, w3.y, acc[nd].y);
            acc[nd].z = fmaf(yv.w, w3.z, acc[nd].z);
            acc[nd].w = fmaf(yv.w, w3.w, acc[nd].w);
        }
    }
#pragma unroll
    for (int nd = 0; nd < 4; nd++)
        *(float4*)(part + kb * 256 + nd * 64 + c0) = acc[nd];
    __syncthreads();
    float v = 0.f;
#pragma unroll
    for (int k2 = 0; k2 < 16; k2++) v += part[k2 * 256 + t];
    int nd = t >> 6, c2 = t & 63;
    int node = nb + nd;
    float ps = v * a_src2[c2];
    float pd = v * a_dst2[c2];
#pragma unroll
    for (int mm = 32; mm >= 1; mm >>= 1) {   // node nd occupies exactly one wave
        ps += __shfl_xor(ps, mm);
        pd += __shfl_xor(pd, mm);
    }
    if (node < N) {
        h2[(size_t)node * 64 + c2] = v;
        if (c2 == 0) { as2[node] = ps; ad2[node] = pd; }
    }
}

// ---------------- Layer 2 aggregate ----------------

__global__ __launch_bounds__(256) void l2_agg(
    const float* __restrict__ h2, const float* __restrict__ as2, const float* __restrict__ ad2,
    const float* __restrict__ b2, const int* __restrict__ offsets, const int* __restrict__ srcs,
    float* __restrict__ out, int N) {
    int n = blockIdx.x;
    int t = threadIdx.x;
    int beg = offsets[n];
    int deg = offsets[n + 1] - beg;
    __shared__ int   ssrc[CHUNK];
    __shared__ float wsh[CHUNK];
    __shared__ float red[256];
    __shared__ float m_sh, s_sh;
    float adn = ad2[n];
    float m = -3.4e38f;
    for (int i = t; i < deg; i += 256) m = fmaxf(m, leaky(as2[srcs[beg + i]] + adn));
    red[t] = m;
    __syncthreads();
    for (int off = 128; off >= 1; off >>= 1) {
        if (t < off) red[t] = fmaxf(red[t], red[t + off]);
        __syncthreads();
    }
    if (t == 0) m_sh = red[0];
    __syncthreads();
    float mv = m_sh;
    int c = t & 63, eg = t >> 6;
    float acc = 0.f, wpart = 0.f;
    for (int cb = 0; cb < deg; cb += CHUNK) {
        int cd = min(CHUNK, deg - cb);
        if (t < cd) {
            int s = srcs[beg + cb + t];
            ssrc[t] = s;
            float w = __expf(leaky(as2[s] + adn) - mv);
            wsh[t] = w;
            wpart += w;
        }
        __syncthreads();
        for (int i = eg; i < cd; i += 4)
            acc = fmaf(wsh[i], h2[(size_t)ssrc[i] * 64 + c], acc);
        __syncthreads();
    }
    red[t] = wpart;
    __syncthreads();
    for (int off = 128; off >= 1; off >>= 1) {
        if (t < off) red[t] += red[t + off];
        __syncthreads();
    }
    if (t == 0) s_sh = red[0] + 1e-16f;
    __syncthreads();
    float stot = s_sh;
    red[t] = acc;
    __syncthreads();
    if (t < 128) red[t] += red[t + 128];
    __syncthreads();
    if (t < 64) {
        float v = red[t] + red[t + 64];
        out[(size_t)n * 64 + t] = v / stot + b2[t];
    }
}

// ---------------- launch ----------------

static inline size_t align_up(size_t v, size_t a) { return (v + a - 1) / a * a; }

extern "C" void kernel_launch(void* const* d_in, const int* in_sizes, int n_in,
                              void* d_out, int out_size, void* d_ws, size_t ws_size,
                              hipStream_t stream) {
    const float* x      = (const float*)d_in[0];
    const int*   ei     = (const int*)d_in[1];
    const float* W1     = (const float*)d_in[2];
    const float* a_src1 = (const float*)d_in[3];
    const float* a_dst1 = (const float*)d_in[4];
    const float* b1     = (const float*)d_in[5];
    const float* W2     = (const float*)d_in[6];
    const float* a_src2 = (const float*)d_in[7];
    const float* a_dst2 = (const float*)d_in[8];
    const float* b2     = (const float*)d_in[9];
    float* out = (float*)d_out;

    int N = in_sizes[0] / 128;
    int E = in_sizes[1] / 2;
    int M = E + N;

    char* p = (char*)d_ws;
    size_t off = 0;
    auto carve = [&](size_t bytes) {
        void* r = p + off;
        off = align_up(off + bytes, 256);
        return r;
    };
    int*   counts  = (int*)carve((size_t)N * 4);
    int*   offsets = (int*)carve((size_t)(N + 1) * 4);
    int*   cursor  = (int*)carve((size_t)N * 4);
    int*   srcs    = (int*)carve((size_t)M * 4);
    float* As      = (float*)carve(1024 * 4);
    float* Ad      = (float*)carve(1024 * 4);
    float* as1     = (float*)carve((size_t)N * 8 * 4);
    float* ad1     = (float*)carve((size_t)N * 8 * 4);
    float* as2     = (float*)carve((size_t)N * 4);
    float* ad2     = (float*)carve((size_t)N * 4);
    float* h2      = (float*)carve((size_t)N * 64 * 4);
    float* y       = (float*)carve((size_t)N * 1024 * 4);
    float* hbuf    = (float*)carve((size_t)N * 1024 * 4);
    (void)ws_size; // ~86 MB

    hipMemsetAsync(counts, 0, (size_t)N * 4, stream);
    prep_kernel<<<4, 256, 0, stream>>>(W1, a_src1, a_dst1, As, Ad);
    alpha1_kernel<<<(N + 31) / 32, 256, 0, stream>>>(x, As, Ad, as1, ad1, N);
    count_kernel<<<(M + 255) / 256, 256, 0, stream>>>(ei, counts, E, N);
    scan_kernel<<<1, 1024, 0, stream>>>(counts, offsets, cursor, N);
    fill_kernel<<<(M + 255) / 256, 256, 0, stream>>>(ei, cursor, srcs, E, N);
    l1_aggx<<<N, 256, 0, stream>>>(x, as1, ad1, offsets, srcs, y, N);
    l1_gemm<<<(N + 7) / 8, 256, 0, stream>>>(y, W1, b1, hbuf, N);
    l2_transform<<<(N + 3) / 4, 256, 0, stream>>>(hbuf, W2, a_src2, a_dst2, h2, as2, ad2, N);
    l2_agg<<<N, 256, 0, stream>>>(h2, as2, ad2, b2, offsets, srcs, out, N);
}

// Round 6
// 267.950 us; speedup vs baseline: 1.2471x; 1.0146x over previous
//
#include <hip/hip_runtime.h>
#include <math.h>

// GAT 2-layer: N=10000, E=160000 (+N self loops), IN=128, H1=8, C1=128, OUT=64.
// R6: l1_gemm exploits per-head block-diagonal structure: block=(32 nodes, head),
//     W1 head-slice (64 KB) staged in LDS once -> W1 L2 traffic 640->160 MB.
//     l2_transform: 8 nodes/block split-K (64 KB LDS) -> W2 traffic 640->320 MB.

#define NEG_SLOPE 0.2f

__device__ __forceinline__ float leaky(float v) { return v >= 0.0f ? v : NEG_SLOPE * v; }

// ---------------- CSR build ----------------

__global__ void count_kernel(const int* __restrict__ ei, int* __restrict__ counts, int E, int N) {
    int i = blockIdx.x * blockDim.x + threadIdx.x;
    int M = E + N;
    if (i >= M) return;
    int dst = (i < E) ? ei[E + i] : (i - E);   // self-loop tail
    atomicAdd(&counts[dst], 1);
}

__global__ __launch_bounds__(1024) void scan_kernel(
    const int* __restrict__ counts, int* __restrict__ offsets,
    int* __restrict__ cursor, int N) {
    __shared__ int sums[1024];
    int t = threadIdx.x;
    int per = (N + 1023) / 1024;
    int base = t * per;
    int s = 0;
    for (int j = 0; j < per; j++) {
        int idx = base + j;
        if (idx < N) s += counts[idx];
    }
    sums[t] = s;
    __syncthreads();
    int acc = s;
    for (int off = 1; off < 1024; off <<= 1) {
        int v = (t >= off) ? sums[t - off] : 0;
        __syncthreads();
        acc += v;
        sums[t] = acc;
        __syncthreads();
    }
    int run = acc - s;
    for (int j = 0; j < per; j++) {
        int idx = base + j;
        if (idx < N) {
            offsets[idx] = run;
            cursor[idx] = run;
            run += counts[idx];
        }
    }
    if (t == 1023) offsets[N] = run;
}

__global__ void fill_kernel(const int* __restrict__ ei, int* __restrict__ cursor,
                            int* __restrict__ srcs, int E, int N) {
    int i = blockIdx.x * blockDim.x + threadIdx.x;
    int M = E + N;
    if (i >= M) return;
    int src, dst;
    if (i < E) { src = ei[i]; dst = ei[E + i]; }
    else       { src = dst = i - E; }
    int pos = atomicAdd(&cursor[dst], 1);
    srcs[pos] = src;
}

// ---------------- prep: As[k,h] = sum_c W1[k,h*128+c]*a_src1[h,c]  (and Ad) ----

__global__ __launch_bounds__(256) void prep_kernel(
    const float* __restrict__ W1, const float* __restrict__ a_src1,
    const float* __restrict__ a_dst1, float* __restrict__ As, float* __restrict__ Ad) {
    int i = blockIdx.x * 256 + threadIdx.x;   // 0..1023
    int k = i >> 3, h = i & 7;
    float ss = 0.f, sd = 0.f;
    for (int c = 0; c < 128; c += 4) {
        float4 w = *(const float4*)(W1 + (size_t)k * 1024 + h * 128 + c);
        float4 a = *(const float4*)(a_src1 + h * 128 + c);
        float4 d = *(const float4*)(a_dst1 + h * 128 + c);
        ss += w.x * a.x + w.y * a.y + w.z * a.z + w.w * a.w;
        sd += w.x * d.x + w.y * d.y + w.z * d.z + w.w * d.w;
    }
    As[k * 8 + h] = ss;
    Ad[k * 8 + h] = sd;
}

// ---------------- alpha1: as1/ad1 = x @ As / Ad  [N,8] ----------------

__global__ __launch_bounds__(256) void alpha1_kernel(
    const float* __restrict__ x, const float* __restrict__ As, const float* __restrict__ Ad,
    float* __restrict__ as1, float* __restrict__ ad1, int N) {
    __shared__ float sAs[1024], sAd[1024];
    int t = threadIdx.x;
    {
        int i = t * 4;
        *(float4*)(sAs + i) = *(const float4*)(As + i);
        *(float4*)(sAd + i) = *(const float4*)(Ad + i);
    }
    __syncthreads();
    int node = blockIdx.x * 32 + (t >> 3);
    int h = t & 7;
    if (node >= N) return;
    float accs = 0.f, accd = 0.f;
    for (int k = 0; k < 128; k += 4) {
        float4 xv = *(const float4*)(x + (size_t)node * 128 + k);
        accs += xv.x * sAs[k * 8 + h] + xv.y * sAs[(k + 1) * 8 + h]
              + xv.z * sAs[(k + 2) * 8 + h] + xv.w * sAs[(k + 3) * 8 + h];
        accd += xv.x * sAd[k * 8 + h] + xv.y * sAd[(k + 1) * 8 + h]
              + xv.z * sAd[(k + 2) * 8 + h] + xv.w * sAd[(k + 3) * 8 + h];
    }
    as1[node * 8 + h] = accs;
    ad1[node * 8 + h] = accd;
}

// ---------------- l1_aggx: y[n,h,:] = sum_e softmax-w * x[src,:] -----------

#define CHUNK 256

__global__ __launch_bounds__(256) void l1_aggx(
    const float* __restrict__ x, const float* __restrict__ as1, const float* __restrict__ ad1,
    const int* __restrict__ offsets, const int* __restrict__ srcs,
    float* __restrict__ y, int N) {
    int n = blockIdx.x;
    int t = threadIdx.x;
    int beg = offsets[n];
    int deg = offsets[n + 1] - beg;
    __shared__ int   ssrc[CHUNK];
    __shared__ float wsh[CHUNK * 8];
    __shared__ float ad[8], mh[8];
    __shared__ float red[256];
    if (t < 8) ad[t] = ad1[n * 8 + t];
    __syncthreads();
    // phase A: per-head max (8 heads x 32 edge-lanes)
    int h8 = t & 7, el = t >> 3;
    float m = -3.4e38f;
    for (int i = el; i < deg; i += 32) {
        int s = srcs[beg + i];
        m = fmaxf(m, leaky(as1[s * 8 + h8] + ad[h8]));
    }
    red[t] = m;
    __syncthreads();
    for (int off = 128; off >= 8; off >>= 1) {
        if (t < off) red[t] = fmaxf(red[t], red[t + off]);
        __syncthreads();
    }
    if (t < 8) mh[t] = red[t];
    __syncthreads();
    // phase B: chunked softmax-weight staging + x-row gather accumulate
    int h = t >> 5;
    int k0 = (t & 31) * 4;
    float ax = 0.f, ay = 0.f, az = 0.f, aw = 0.f, ssum = 0.f;
    for (int cb = 0; cb < deg; cb += CHUNK) {
        int cd = min(CHUNK, deg - cb);
        if (t < cd) ssrc[t] = srcs[beg + cb + t];
        __syncthreads();
        for (int idx = t; idx < cd * 8; idx += 256) {
            int i = idx >> 3, hx = idx & 7;
            int s = ssrc[i];
            wsh[idx] = __expf(leaky(as1[s * 8 + hx] + ad[hx]) - mh[hx]);
        }
        __syncthreads();
        int i = 0;
        for (; i + 1 < cd; i += 2) {
            int s0 = ssrc[i], s1 = ssrc[i + 1];
            float w0 = wsh[i * 8 + h], w1 = wsh[(i + 1) * 8 + h];
            float4 v0 = *(const float4*)(x + (size_t)s0 * 128 + k0);
            float4 v1 = *(const float4*)(x + (size_t)s1 * 128 + k0);
            ax = fmaf(w0, v0.x, ax); ay = fmaf(w0, v0.y, ay);
            az = fmaf(w0, v0.z, az); aw = fmaf(w0, v0.w, aw);
            ax = fmaf(w1, v1.x, ax); ay = fmaf(w1, v1.y, ay);
            az = fmaf(w1, v1.z, az); aw = fmaf(w1, v1.w, aw);
            ssum += w0 + w1;
        }
        if (i < cd) {
            int s0 = ssrc[i];
            float w0 = wsh[i * 8 + h];
            float4 v0 = *(const float4*)(x + (size_t)s0 * 128 + k0);
            ax = fmaf(w0, v0.x, ax); ay = fmaf(w0, v0.y, ay);
            az = fmaf(w0, v0.z, az); aw = fmaf(w0, v0.w, aw);
            ssum += w0;
        }
        __syncthreads();
    }
    float inv = 1.0f / (ssum + 1e-16f);
    *(float4*)(y + (size_t)n * 1024 + t * 4) =
        make_float4(ax * inv, ay * inv, az * inv, aw * inv);
}

// ---------------- l1_gemm: hbuf = ELU(per-head y @ W1h + b1) ----------------
// Block = (32-node tile, head h). LDS: W1h 64 KB + y-slice 16 KB = 80 KB
// (2 blocks/CU). W1h read from L2 exactly once per block. Thread:
// ng=t>>5 (4 nodes), c0=(t&31)*4. Grid = ceil(N/32)*8 = 2504.

__global__ __launch_bounds__(256) void l1_gemm(
    const float* __restrict__ y, const float* __restrict__ W1,
    const float* __restrict__ b1, float* __restrict__ hbuf, int N) {
    int h = blockIdx.x & 7;
    int nb = (blockIdx.x >> 3) * 32;
    int t = threadIdx.x;
    __shared__ float Wsh[128 * 128];   // 64 KB: W1h[k][c]
    __shared__ float ys[32 * 128];     // 16 KB
    // stage W1h: 4096 float4, 16 per thread, coalesced (8 rows per r-iter)
#pragma unroll
    for (int r = 0; r < 16; r++) {
        int idx = r * 256 + t;          // float4 index
        int k = idx >> 5, fq = idx & 31;
        float4 w = *(const float4*)(W1 + (size_t)k * 1024 + h * 128 + fq * 4);
        *(float4*)(Wsh + k * 128 + fq * 4) = w;
    }
    // stage y slice: 1024 float4, 4 per thread
#pragma unroll
    for (int r = 0; r < 4; r++) {
        int idx = r * 256 + t;
        int nd = idx >> 5, fq = idx & 31;
        int node = nb + nd;
        float4 v = make_float4(0.f, 0.f, 0.f, 0.f);
        if (node < N) v = *(const float4*)(y + (size_t)node * 1024 + h * 128 + fq * 4);
        *(float4*)(ys + nd * 128 + fq * 4) = v;
    }
    __syncthreads();
    int c0 = (t & 31) * 4;
    int ng = t >> 5;           // nodes ng*4 .. ng*4+3
    float4 acc[4];
#pragma unroll
    for (int nd = 0; nd < 4; nd++) acc[nd] = make_float4(0.f, 0.f, 0.f, 0.f);
    for (int k = 0; k < 128; k += 4) {
        float4 w0 = *(const float4*)(Wsh + (k + 0) * 128 + c0);
        float4 w1 = *(const float4*)(Wsh + (k + 1) * 128 + c0);
        float4 w2 = *(const float4*)(Wsh + (k + 2) * 128 + c0);
        float4 w3 = *(const float4*)(Wsh + (k + 3) * 128 + c0);
#pragma unroll
        for (int nd = 0; nd < 4; nd++) {
            float4 yv = *(const float4*)(ys + (ng * 4 + nd) * 128 + k);  // broadcast
            acc[nd].x = fmaf(yv.x, w0.x, acc[nd].x);
            acc[nd].y = fmaf(yv.x, w0.y, acc[nd].y);
            acc[nd].z = fmaf(yv.x, w0.z, acc[nd].z);
            acc[nd].w = fmaf(yv.x, w0.w, acc[nd].w);
            acc[nd].x = fmaf(yv.y, w1.x, acc[nd].x);
            acc[nd].y = fmaf(yv.y, w1.y, acc[nd].y);
            acc[nd].z = fmaf(yv.y, w1.z, acc[nd].z);
            acc[nd].w = fmaf(yv.y, w1.w, acc[nd].w);
            acc[nd].x = fmaf(yv.z, w2.x, acc[nd].x);
            acc[nd].y = fmaf(yv.z, w2.y, acc[nd].y);
            acc[nd].z = fmaf(yv.z, w2.z, acc[nd].z);
            acc[nd].w = fmaf(yv.z, w2.w, acc[nd].w);
            acc[nd].x = fmaf(yv.w, w3.x, acc[nd].x);
            acc[nd].y = fmaf(yv.w, w3.y, acc[nd].y);
            acc[nd].z = fmaf(yv.w, w3.z, acc[nd].z);
            acc[nd].w = fmaf(yv.w, w3.w, acc[nd].w);
        }
    }
    float4 bv = *(const float4*)(b1 + h * 128 + c0);
#pragma unroll
    for (int nd = 0; nd < 4; nd++) {
        int node = nb + ng * 4 + nd;
        if (node >= N) break;
        float ox = acc[nd].x + bv.x;
        float oy = acc[nd].y + bv.y;
        float oz = acc[nd].z + bv.z;
        float ow = acc[nd].w + bv.w;
        ox = ox > 0.f ? ox : expm1f(ox);
        oy = oy > 0.f ? oy : expm1f(oy);
        oz = oz > 0.f ? oz : expm1f(oz);
        ow = ow > 0.f ? ow : expm1f(ow);
        *(float4*)(hbuf + (size_t)node * 1024 + h * 128 + c0) = make_float4(ox, oy, oz, ow);
    }
}

// ---------------- Layer 2 transform: h2 = hbuf @ W2, alpha_s2/alpha_d2 ------
// Split-K: 8 nodes/block, thread = (cg=t&15 -> 4 ch, kb=t>>4 -> 64 k).
// W2 read once per block (320 MB L2 total). LDS: hs 32 KB + part 32 KB.
// Grid = ceil(N/8) = 1250.

__global__ __launch_bounds__(256) void l2_transform(
    const float* __restrict__ hbuf, const float* __restrict__ W2,
    const float* __restrict__ a_src2, const float* __restrict__ a_dst2,
    float* __restrict__ h2, float* __restrict__ as2, float* __restrict__ ad2, int N) {
    int nb = blockIdx.x * 8;
    int t = threadIdx.x;
    __shared__ float hs[8 * 1024];     // 32 KB
    __shared__ float part[16 * 512];   // 32 KB
#pragma unroll
    for (int r = 0; r < 8; r++) {
        int idx = r * 1024 + t * 4;
        int node = nb + (idx >> 10);
        float4 v = make_float4(0.f, 0.f, 0.f, 0.f);
        if (node < N) v = *(const float4*)(hbuf + (size_t)node * 1024 + (idx & 1023));
        *(float4*)(hs + idx) = v;
    }
    __syncthreads();
    int cg = t & 15, kb = t >> 4;
    int c0 = cg * 4;
    int kbase = kb * 64;
    float4 acc[8];
#pragma unroll
    for (int nd = 0; nd < 8; nd++) acc[nd] = make_float4(0.f, 0.f, 0.f, 0.f);
    for (int jj = 0; jj < 64; jj += 4) {
        int k = kbase + ((jj + kb * 16) & 63);   // stagger: <=2-way bank overlap
        float4 w0 = *(const float4*)(W2 + (size_t)(k + 0) * 64 + c0);
        float4 w1 = *(const float4*)(W2 + (size_t)(k + 1) * 64 + c0);
        float4 w2 = *(const float4*)(W2 + (size_t)(k + 2) * 64 + c0);
        float4 w3 = *(const float4*)(W2 + (size_t)(k + 3) * 64 + c0);
#pragma unroll
        for (int nd = 0; nd < 8; nd++) {
            float4 yv = *(const float4*)(hs + nd * 1024 + k);
            acc[nd].x = fmaf(yv.x, w0.x, acc[nd].x);
            acc[nd].y = fmaf(yv.x, w0.y, acc[nd].y);
            acc[nd].z = fmaf(yv.x, w0.z, acc[nd].z);
            acc[nd].w = fmaf(yv.x, w0.w, acc[nd].w);
            acc[nd].x = fmaf(yv.y, w1.x, acc[nd].x);
            acc[nd].y = fmaf(yv.y, w1.y, acc[nd].y);
            acc[nd].z = fmaf(yv.y, w1.z, acc[nd].z);
            acc[nd].w = fmaf(yv.y, w1.w, acc[nd].w);
            acc[nd].x = fmaf(yv.z, w2.x, acc[nd].x);
            acc[nd].y = fmaf(yv.z, w2.y, acc[nd].y);
            acc[nd].z = fmaf(yv.z, w2.z, acc[nd].z);
            acc[nd].w = fmaf(yv.z, w2.w, acc[nd].w);
            acc[nd].x = fmaf(yv.w, w3.x, acc[nd].x);
            acc[nd].y = fmaf(yv.w, w3.y, acc[nd].y);
            acc[nd].z = fmaf(yv.w, w3.z, acc[nd].z);
            acc[nd].w = fmaf(yv.w, w3.w, acc[nd].w);
        }
    }
#pragma unroll
    for (int nd = 0; nd < 8; nd++)
        *(float4*)(part + kb * 512 + nd * 64 + c0) = acc[nd];
    __syncthreads();
#pragma unroll
    for (int r = 0; r < 2; r++) {
        int oi = t + r * 256;            // nd*64 + c2
        float v = 0.f;
#pragma unroll
        for (int k2 = 0; k2 < 16; k2++) v += part[k2 * 512 + oi];
        int nd = oi >> 6, c2 = t & 63;
        int node = nb + nd;
        float ps = v * a_src2[c2];
        float pd = v * a_dst2[c2];
#pragma unroll
        for (int mm = 32; mm >= 1; mm >>= 1) {   // node nd occupies exactly one wave
            ps += __shfl_xor(ps, mm);
            pd += __shfl_xor(pd, mm);
        }
        if (node < N) {
            h2[(size_t)node * 64 + c2] = v;
            if (c2 == 0) { as2[node] = ps; ad2[node] = pd; }
        }
    }
}

// ---------------- Layer 2 aggregate ----------------

__global__ __launch_bounds__(256) void l2_agg(
    const float* __restrict__ h2, const float* __restrict__ as2, const float* __restrict__ ad2,
    const float* __restrict__ b2, const int* __restrict__ offsets, const int* __restrict__ srcs,
    float* __restrict__ out, int N) {
    int n = blockIdx.x;
    int t = threadIdx.x;
    int beg = offsets[n];
    int deg = offsets[n + 1] - beg;
    __shared__ int   ssrc[CHUNK];
    __shared__ float wsh[CHUNK];
    __shared__ float red[256];
    __shared__ float m_sh, s_sh;
    float adn = ad2[n];
    float m = -3.4e38f;
    for (int i = t; i < deg; i += 256) m = fmaxf(m, leaky(as2[srcs[beg + i]] + adn));
    red[t] = m;
    __syncthreads();
    for (int off = 128; off >= 1; off >>= 1) {
        if (t < off) red[t] = fmaxf(red[t], red[t + off]);
        __syncthreads();
    }
    if (t == 0) m_sh = red[0];
    __syncthreads();
    float mv = m_sh;
    int c = t & 63, eg = t >> 6;
    float acc = 0.f, wpart = 0.f;
    for (int cb = 0; cb < deg; cb += CHUNK) {
        int cd = min(CHUNK, deg - cb);
        if (t < cd) {
            int s = srcs[beg + cb + t];
            ssrc[t] = s;
            float w = __expf(leaky(as2[s] + adn) - mv);
            wsh[t] = w;
            wpart += w;
        }
        __syncthreads();
        for (int i = eg; i < cd; i += 4)
            acc = fmaf(wsh[i], h2[(size_t)ssrc[i] * 64 + c], acc);
        __syncthreads();
    }
    red[t] = wpart;
    __syncthreads();
    for (int off = 128; off >= 1; off >>= 1) {
        if (t < off) red[t] += red[t + off];
        __syncthreads();
    }
    if (t == 0) s_sh = red[0] + 1e-16f;
    __syncthreads();
    float stot = s_sh;
    red[t] = acc;
    __syncthreads();
    if (t < 128) red[t] += red[t + 128];
    __syncthreads();
    if (t < 64) {
        float v = red[t] + red[t + 64];
        out[(size_t)n * 64 + t] = v / stot + b2[t];
    }
}

// ---------------- launch ----------------

static inline size_t align_up(size_t v, size_t a) { return (v + a - 1) / a * a; }

extern "C" void kernel_launch(void* const* d_in, const int* in_sizes, int n_in,
                              void* d_out, int out_size, void* d_ws, size_t ws_size,
                              hipStream_t stream) {
    const float* x      = (const float*)d_in[0];
    const int*   ei     = (const int*)d_in[1];
    const float* W1     = (const float*)d_in[2];
    const float* a_src1 = (const float*)d_in[3];
    const float* a_dst1 = (const float*)d_in[4];
    const float* b1     = (const float*)d_in[5];
    const float* W2     = (const float*)d_in[6];
    const float* a_src2 = (const float*)d_in[7];
    const float* a_dst2 = (const float*)d_in[8];
    const float* b2     = (const float*)d_in[9];
    float* out = (float*)d_out;

    int N = in_sizes[0] / 128;
    int E = in_sizes[1] / 2;
    int M = E + N;

    char* p = (char*)d_ws;
    size_t off = 0;
    auto carve = [&](size_t bytes) {
        void* r = p + off;
        off = align_up(off + bytes, 256);
        return r;
    };
    int*   counts  = (int*)carve((size_t)N * 4);
    int*   offsets = (int*)carve((size_t)(N + 1) * 4);
    int*   cursor  = (int*)carve((size_t)N * 4);
    int*   srcs    = (int*)carve((size_t)M * 4);
    float* As      = (float*)carve(1024 * 4);
    float* Ad      = (float*)carve(1024 * 4);
    float* as1     = (float*)carve((size_t)N * 8 * 4);
    float* ad1     = (float*)carve((size_t)N * 8 * 4);
    float* as2     = (float*)carve((size_t)N * 4);
    float* ad2     = (float*)carve((size_t)N * 4);
    float* h2      = (float*)carve((size_t)N * 64 * 4);
    float* y       = (float*)carve((size_t)N * 1024 * 4);
    float* hbuf    = (float*)carve((size_t)N * 1024 * 4);
    (void)ws_size; // ~86 MB

    hipMemsetAsync(counts, 0, (size_t)N * 4, stream);
    prep_kernel<<<4, 256, 0, stream>>>(W1, a_src1, a_dst1, As, Ad);
    alpha1_kernel<<<(N + 31) / 32, 256, 0, stream>>>(x, As, Ad, as1, ad1, N);
    count_kernel<<<(M + 255) / 256, 256, 0, stream>>>(ei, counts, E, N);
    scan_kernel<<<1, 1024, 0, stream>>>(counts, offsets, cursor, N);
    fill_kernel<<<(M + 255) / 256, 256, 0, stream>>>(ei, cursor, srcs, E, N);
    l1_aggx<<<N, 256, 0, stream>>>(x, as1, ad1, offsets, srcs, y, N);
    l1_gemm<<<((N + 31) / 32) * 8, 256, 0, stream>>>(y, W1, b1, hbuf, N);
    l2_transform<<<(N + 7) / 8, 256, 0, stream>>>(hbuf, W2, a_src2, a_dst2, h2, as2, ad2, N);
    l2_agg<<<N, 256, 0, stream>>>(h2, as2, ad2, b2, offsets, srcs, out, N);
}